// Round 11
// baseline (234.998 us; speedup 1.0000x reference)
//
#include <hip/hip_runtime.h>

// DiceCoefficientAll: B=8, N_per_batch=128^3, labels in [0,14)
// ws: u32 gcnt[8][3][14] + u32 ticket  (memset-zeroed each launch)

#define NL 14
#define NBATCH 8
constexpr float EPSF = 2.220446049250313e-16f;  // np.finfo(float).eps

typedef unsigned int u32;
typedef unsigned long long u64;
typedef float f32x4 __attribute__((ext_vector_type(4)));  // nt-builtin-compatible

// Block: 256 threads x 32 elements = 8192 contiguous elements; 2048 blocks.
// nt loads (R9: lifted the ~2.8 TB/s per-CU L1-allocation cap; hist <40us)
// + asm-pinned 16-load batch + shfl flush. R10: last block finalizes in-place
// (ticket after fence; atomic re-reads of gcnt for coherent-point access).
__global__ __launch_bounds__(256) void dice_hist_kernel(
    const float* __restrict__ s1, const float* __restrict__ s2,
    u32* __restrict__ gcnt, float* __restrict__ out) {
  __shared__ u32 sh[3 * NL];
  __shared__ int last_flag;
  const int tid = threadIdx.x;
  const int lane = tid & 63;
  if (tid < 3 * NL) sh[tid] = 0;
  __syncthreads();

  const f32x4* __restrict__ p1 = (const f32x4*)s1 + (size_t)blockIdx.x * 2048 + tid;
  const f32x4* __restrict__ p2 = (const f32x4*)s2 + (size_t)blockIdx.x * 2048 + tid;

  // ---- Load phase: 16 non-temporal global_load_dwordx4, all issued first ----
  f32x4 A[8], B[8];
#pragma unroll
  for (int k = 0; k < 8; ++k) {
    A[k] = __builtin_nontemporal_load(p1 + (size_t)k * 256);
    B[k] = __builtin_nontemporal_load(p2 + (size_t)k * 256);
  }
  __builtin_amdgcn_sched_barrier(0);  // all 16 issued before any pin/wait
  // Value fences: loads cannot sink past these; forces the full batch live.
#pragma unroll
  for (int k = 0; k < 8; ++k) {
    asm volatile("" : "+v"(A[k]), "+v"(B[k]));
  }

  // ---- Compute: packed 8-bit-field register histograms (max 32 < 255) ----
  u64 c1lo = 0, c1hi = 0, c2lo = 0, c2hi = 0, cilo = 0, cihi = 0;
#pragma unroll
  for (int k = 0; k < 8; ++k) {
    float av[4] = {A[k].x, A[k].y, A[k].z, A[k].w};
    float bv[4] = {B[k].x, B[k].y, B[k].z, B[k].w};
#pragma unroll
    for (int j = 0; j < 4; ++j) {
      int i1 = (int)av[j];
      int i2 = (int)bv[j];
      int ia = (i1 == i2) ? i1 : 14;  // overflow bin for mismatches
      { u64 inc = 1ULL << ((i1 << 3) & 63); bool h = i1 >= 8;
        c1lo += h ? 0ULL : inc; c1hi += h ? inc : 0ULL; }
      { u64 inc = 1ULL << ((i2 << 3) & 63); bool h = i2 >= 8;
        c2lo += h ? 0ULL : inc; c2hi += h ? inc : 0ULL; }
      { u64 inc = 1ULL << ((ia << 3) & 63); bool h = ia >= 8;
        cilo += h ? 0ULL : inc; cihi += h ? inc : 0ULL; }
    }
  }

  // Depth-2 cross-lane packed reduce (4-lane sums, max 128 < 255: no overflow).
  c1lo += __shfl_xor(c1lo, 1); c1lo += __shfl_xor(c1lo, 2);
  c1hi += __shfl_xor(c1hi, 1); c1hi += __shfl_xor(c1hi, 2);
  c2lo += __shfl_xor(c2lo, 1); c2lo += __shfl_xor(c2lo, 2);
  c2hi += __shfl_xor(c2hi, 1); c2hi += __shfl_xor(c2hi, 2);
  cilo += __shfl_xor(cilo, 1); cilo += __shfl_xor(cilo, 2);
  cihi += __shfl_xor(cihi, 1); cihi += __shfl_xor(cihi, 2);

  // 16 leader lanes/wave, staggered start bin (0 bank conflicts measured in R5).
  if ((lane & 3) == 0) {
    int l = (lane >> 2) % NL;
#pragma unroll
    for (int j = 0; j < NL; ++j) {
      const int sh8 = (l << 3) & 63;
      const bool h = l >= 8;
      u32 v1 = (u32)(((h ? c1hi : c1lo) >> sh8) & 0xFF);
      u32 v2 = (u32)(((h ? c2hi : c2lo) >> sh8) & 0xFF);
      u32 vi = (u32)(((h ? cihi : cilo) >> sh8) & 0xFF);
      atomicAdd(&sh[l], v1);
      atomicAdd(&sh[NL + l], v2);
      atomicAdd(&sh[2 * NL + l], vi);
      l = (l == NL - 1) ? 0 : l + 1;
    }
  }
  __syncthreads();

  if (tid < 3 * NL) {
    const int batch = blockIdx.x >> 8;  // 256 blocks per batch
    atomicAdd(&gcnt[batch * 3 * NL + tid], sh[tid]);
  }

  // ---- Last-block finalize (replaces the separate final kernel) ----
  u32* ticket = gcnt + NBATCH * 3 * NL;
  __syncthreads();  // all 42 block-atomics issued
  if (tid == 0) {
    __threadfence();  // block's atomics globally visible before ticket bump
    last_flag = (atomicAdd(ticket, 1u) == (u32)(gridDim.x - 1)) ? 1 : 0;
  }
  __syncthreads();
  if (!last_flag) return;

  // Atomic re-reads: coherent-point access (plain loads could hit a stale
  // per-XCD L2 line; G16).
  __shared__ float fsum[128];
  __shared__ int fcnt[128];
  __shared__ u32 tot[3 * NL * NBATCH];
  for (int i = tid; i < 3 * NL * NBATCH; i += 256) {
    tot[i] = atomicAdd(&gcnt[i], 0u);
  }
  __syncthreads();
  if (tid < 128) {
    float v = 0.0f;
    int nz = 0;
    if (tid < NBATCH * NL) {
      const int b = tid / NL, l = tid % NL;
      const u32* g = tot + b * 3 * NL;
      const float c1 = (float)g[l];
      const float c2 = (float)g[NL + l];
      const float ci = (float)g[2 * NL + l];
      v = 2.0f * ci / (c1 + c2 + EPSF);
      nz = (v > 0.0f) ? 1 : 0;
    }
    fsum[tid] = v;
    fcnt[tid] = nz;
  }
  __syncthreads();
  for (int s = 64; s > 0; s >>= 1) {
    if (tid < s && tid + s < 128) {
      fsum[tid] += fsum[tid + s];
      fcnt[tid] += fcnt[tid + s];
    }
    __syncthreads();
  }
  if (tid == 0) out[0] = fcnt[0] ? (fsum[0] / (float)fcnt[0]) : 0.0f;
}

extern "C" void kernel_launch(void* const* d_in, const int* in_sizes, int n_in,
                              void* d_out, int out_size, void* d_ws, size_t ws_size,
                              hipStream_t stream) {
  const float* s1 = (const float*)d_in[0];
  const float* s2 = (const float*)d_in[1];
  u32* gcnt = (u32*)d_ws;  // 8*3*14 u32 + 1 ticket = 1348 B
  (void)hipMemsetAsync(gcnt, 0, (NBATCH * 3 * NL + 1) * sizeof(u32), stream);
  const int n = in_sizes[0];    // 16,777,216 expected
  const int blocks = n / 8192;  // 8192 elements per block -> 2048 blocks
  dice_hist_kernel<<<blocks, 256, 0, stream>>>(s1, s2, gcnt, (float*)d_out);
}

// Round 13
// 148.510 us; speedup vs baseline: 1.5824x; 1.5824x over previous
//
#include <hip/hip_runtime.h>

// DiceCoefficientAll: B=8, N_per_batch=128^3, labels in [0,14)
// ws: u32 gcnt[8][3][14]  (hist 0 = count1, 1 = count2, 2 = intersection)
//
// R9-champion config (graded 148.7 us, hist < 40 us):
//  - nt loads: bypass L1 line allocation -> lifted the ~2.8 TB/s per-CU cap
//    (R3/R4/R5 all ~50 us regardless of schedule; R9 dropped below the 40 us
//    poison fills).
//  - two kernels; NO per-block __threadfence/ticket: R11 showed agent-scope
//    release fences (buffer_wbl2 sc1, XCD-L2 writeback) from 2048 blocks
//    serialize the TCC pipeline: hist 50->120 us, graded 149->235.

#define NL 14
#define NBATCH 8
constexpr float EPSF = 2.220446049250313e-16f;  // np.finfo(float).eps

typedef unsigned int u32;
typedef unsigned long long u64;
typedef float f32x4 __attribute__((ext_vector_type(4)));  // nt-builtin-compatible

// Block: 256 threads x 32 elements = 8192 contiguous elements; 2048 blocks.
__global__ __launch_bounds__(256) void dice_hist_kernel(
    const float* __restrict__ s1, const float* __restrict__ s2,
    u32* __restrict__ gcnt) {
  __shared__ u32 sh[3 * NL];
  const int tid = threadIdx.x;
  const int lane = tid & 63;
  if (tid < 3 * NL) sh[tid] = 0;
  __syncthreads();

  const f32x4* __restrict__ p1 = (const f32x4*)s1 + (size_t)blockIdx.x * 2048 + tid;
  const f32x4* __restrict__ p2 = (const f32x4*)s2 + (size_t)blockIdx.x * 2048 + tid;

  // ---- Load phase: 16 non-temporal global_load_dwordx4, all issued first ----
  f32x4 A[8], B[8];
#pragma unroll
  for (int k = 0; k < 8; ++k) {
    A[k] = __builtin_nontemporal_load(p1 + (size_t)k * 256);
    B[k] = __builtin_nontemporal_load(p2 + (size_t)k * 256);
  }
  __builtin_amdgcn_sched_barrier(0);  // all 16 issued before any pin/wait
  // Value fences: loads cannot sink past these; forces the full batch live.
#pragma unroll
  for (int k = 0; k < 8; ++k) {
    asm volatile("" : "+v"(A[k]), "+v"(B[k]));
  }

  // ---- Compute: packed 8-bit-field register histograms (max 32 < 255) ----
  u64 c1lo = 0, c1hi = 0, c2lo = 0, c2hi = 0, cilo = 0, cihi = 0;
#pragma unroll
  for (int k = 0; k < 8; ++k) {
    float av[4] = {A[k].x, A[k].y, A[k].z, A[k].w};
    float bv[4] = {B[k].x, B[k].y, B[k].z, B[k].w};
#pragma unroll
    for (int j = 0; j < 4; ++j) {
      int i1 = (int)av[j];
      int i2 = (int)bv[j];
      int ia = (i1 == i2) ? i1 : 14;  // overflow bin for mismatches
      { u64 inc = 1ULL << ((i1 << 3) & 63); bool h = i1 >= 8;
        c1lo += h ? 0ULL : inc; c1hi += h ? inc : 0ULL; }
      { u64 inc = 1ULL << ((i2 << 3) & 63); bool h = i2 >= 8;
        c2lo += h ? 0ULL : inc; c2hi += h ? inc : 0ULL; }
      { u64 inc = 1ULL << ((ia << 3) & 63); bool h = ia >= 8;
        cilo += h ? 0ULL : inc; cihi += h ? inc : 0ULL; }
    }
  }

  // Depth-2 cross-lane packed reduce (4-lane sums, max 128 < 255: no overflow).
  c1lo += __shfl_xor(c1lo, 1); c1lo += __shfl_xor(c1lo, 2);
  c1hi += __shfl_xor(c1hi, 1); c1hi += __shfl_xor(c1hi, 2);
  c2lo += __shfl_xor(c2lo, 1); c2lo += __shfl_xor(c2lo, 2);
  c2hi += __shfl_xor(c2hi, 1); c2hi += __shfl_xor(c2hi, 2);
  cilo += __shfl_xor(cilo, 1); cilo += __shfl_xor(cilo, 2);
  cihi += __shfl_xor(cihi, 1); cihi += __shfl_xor(cihi, 2);

  // 16 leader lanes/wave, staggered start bin (0 bank conflicts measured in R5).
  if ((lane & 3) == 0) {
    int l = (lane >> 2) % NL;
#pragma unroll
    for (int j = 0; j < NL; ++j) {
      const int sh8 = (l << 3) & 63;
      const bool h = l >= 8;
      u32 v1 = (u32)(((h ? c1hi : c1lo) >> sh8) & 0xFF);
      u32 v2 = (u32)(((h ? c2hi : c2lo) >> sh8) & 0xFF);
      u32 vi = (u32)(((h ? cihi : cilo) >> sh8) & 0xFF);
      atomicAdd(&sh[l], v1);
      atomicAdd(&sh[NL + l], v2);
      atomicAdd(&sh[2 * NL + l], vi);
      l = (l == NL - 1) ? 0 : l + 1;
    }
  }
  __syncthreads();

  if (tid < 3 * NL) {
    const int batch = blockIdx.x >> 8;  // 256 blocks per batch
    atomicAdd(&gcnt[batch * 3 * NL + tid], sh[tid]);
  }
}

__global__ __launch_bounds__(128) void dice_final_kernel(
    const u32* __restrict__ gcnt, float* __restrict__ out) {
  __shared__ float ssum[128];
  __shared__ int scnt[128];
  const int t = threadIdx.x;
  float v = 0.0f;
  int nz = 0;
  if (t < NBATCH * NL) {
    const int b = t / NL, l = t % NL;
    const u32* g = gcnt + b * 3 * NL;
    const float c1 = (float)g[l];
    const float c2 = (float)g[NL + l];
    const float ci = (float)g[2 * NL + l];
    v = 2.0f * ci / (c1 + c2 + EPSF);
    nz = (v > 0.0f) ? 1 : 0;
  }
  ssum[t] = v;
  scnt[t] = nz;
  __syncthreads();
  for (int s = 64; s > 0; s >>= 1) {
    if (t < s) {
      ssum[t] += ssum[t + s];
      scnt[t] += scnt[t + s];
    }
    __syncthreads();
  }
  if (t == 0) out[0] = scnt[0] ? (ssum[0] / (float)scnt[0]) : 0.0f;
}

extern "C" void kernel_launch(void* const* d_in, const int* in_sizes, int n_in,
                              void* d_out, int out_size, void* d_ws, size_t ws_size,
                              hipStream_t stream) {
  const float* s1 = (const float*)d_in[0];
  const float* s2 = (const float*)d_in[1];
  u32* gcnt = (u32*)d_ws;  // 8*3*14 u32 = 1344 B
  (void)hipMemsetAsync(gcnt, 0, NBATCH * 3 * NL * sizeof(u32), stream);
  const int n = in_sizes[0];    // 16,777,216 expected
  const int blocks = n / 8192;  // 8192 elements per block -> 2048 blocks
  dice_hist_kernel<<<blocks, 256, 0, stream>>>(s1, s2, gcnt);
  dice_final_kernel<<<1, 128, 0, stream>>>(gcnt, (float*)d_out);
}